// Round 2
// baseline (840.421 us; speedup 1.0000x reference)
//
#include <hip/hip_runtime.h>
#include <stdint.h>

typedef unsigned int u32;
typedef unsigned long long u64;
typedef _Float16 f16;
typedef __attribute__((ext_vector_type(8))) _Float16 f16x8;
typedef __attribute__((ext_vector_type(4))) _Float16 f16x4;
typedef __attribute__((ext_vector_type(2))) _Float16 f16x2;
typedef __attribute__((ext_vector_type(4))) float f32x4;

#define MFMA16(a, b, c) __builtin_amdgcn_mfma_f32_16x16x32_f16((a), (b), (c), 0, 0, 0)
#define MARGIN 2.0f

__device__ __forceinline__ u32 ford(float x) { u32 u = __float_as_uint(x); return (u & 0x80000000u) ? ~u : (u | 0x80000000u); }
__device__ __forceinline__ float iford(u32 v) { u32 u = (v & 0x80000000u) ? (v & 0x7FFFFFFFu) : ~v; return __uint_as_float(u); }
__device__ __forceinline__ int xswz(int i, int n) { return (i & 7) * (n >> 3) + (i >> 3); }  // n%8==0
__device__ __forceinline__ u32 pkf16(float a, float b) {
  f16x2 p; p[0] = (f16)a; p[1] = (f16)b; u32 r; __builtin_memcpy(&r, &p, 4); return r;
}

// ---------------------------------------------------------------------------
// NT-GEMM, 128x128 tile, BK=64, 256 thr (4 waves, 2x2 x 64x64), mfma 16x16x32 f16.
// MODE 0 (K1): A = x fp32 (subtract seq_last, *16, split f16 hi/lo in staging),
//              B = w_in pre-split f16 hi/lo (*1024). 3-pass. out f fp32 (/16384 + b_in).
// MODE 1 (Ep): A = ef16, B = w_out f16 slice. out f16.
// MODE 2 (gram): A=B=nT f16. sum(C^2) -> fixed-point atomic.
// MODE 3 (screen): A = f fp32 -> f16 cast, B = ef16 head. score=esq-2S; candidates.
// MODE 4 (y): A = wlin f16, B = qT f16. out fp32 + b_lin[m] + seq_last[n].
// ---------------------------------------------------------------------------
template <int MODE>
__global__ __launch_bounds__(256, 2) void gemm_nt(
    const float* __restrict__ Af, const f16* __restrict__ Ah,
    const f16* __restrict__ Bh, const f16* __restrict__ Bl,
    int n0, int kchunks, void* __restrict__ out0,
    const float* __restrict__ bias, const float* __restrict__ aux,
    u64* __restrict__ slots) {
  constexpr bool K1 = (MODE == 0);
  constexpr int LDA = (MODE == 2 || MODE == 4) ? 1024 : 512;
  constexpr int LDB = (MODE == 1) ? 2048 : ((MODE == 2 || MODE == 4) ? 1024 : 512);
  constexpr int LDS_SZ = K1 ? 65536 : (MODE == 3 ? 41472 : 32768);
  __shared__ char lds[LDS_SZ];
  char* sA = lds;                                   // A hi
  char* sB = lds + (K1 ? 32768 : 16384);            // B hi
  char* sAl = lds + 16384;                          // A lo (K1)
  char* sBl = lds + 49152;                          // B lo (K1)

  const int tid = threadIdx.x;
  const int lane = tid & 63, wid = tid >> 6;
  const int wm = wid >> 1, wn = wid & 1;

  int blkm, blkn, z = 0;
  if constexpr (MODE == 0) { int s = xswz(blockIdx.x, 512); blkn = s & 3; blkm = s >> 2; }
  else if constexpr (MODE == 1) { int s = xswz(blockIdx.x, 128); blkn = s & 3; blkm = (s >> 2) & 7; z = s >> 5; }
  else if constexpr (MODE == 2) { int s = xswz(blockIdx.x, 64); blkn = s & 3; blkm = (s >> 2) & 3; z = s >> 4; }
  else if constexpr (MODE == 3) { int s = xswz(blockIdx.x, 1024); blkn = s & 7; blkm = s >> 3; }
  else { int s = xswz(blockIdx.x, 768); blkm = s % 6; blkn = (s / 6) & 3; z = s / 24; }

  if constexpr (MODE == 3) {
    u64* candL = (u64*)(lds + 32768);
    int* cntL = (int*)(lds + 40960);
    for (int i = tid; i < 1024; i += 256) candL[i] = ~0ull;
    if (tid < 128) cntL[tid] = 0;
  }

  // base pointers (blkm/blkn folded where possible)
  const f16* A16 = nullptr;
  const f16* B16 = nullptr;
  const f16* B16l = nullptr;
  const float* A32 = nullptr;
  if constexpr (MODE == 0) {
    A32 = Af;  // needs global row (seq_last), offset in staging
    B16 = Bh + (size_t)blkn * 128 * 512;
    B16l = Bl + (size_t)blkn * 128 * 512;
  } else if constexpr (MODE == 1) {
    A16 = Ah + (size_t)z * 524288 + (size_t)blkm * 128 * 512;
    B16 = Bh + (size_t)z * 512 + (size_t)blkn * 128 * 2048;
  } else if constexpr (MODE == 2) {
    A16 = Ah + (size_t)z * 524288 + (size_t)blkm * 128 * 1024;
    B16 = Bh + (size_t)z * 524288 + (size_t)blkn * 128 * 1024;
  } else if constexpr (MODE == 3) {
    A32 = Af + (size_t)blkm * 128 * 512;
    B16 = Bh + (size_t)blkn * 128 * 512;
  } else {
    A16 = Ah + (size_t)blkm * 128 * 1024;
    B16 = Bh + (size_t)z * 524288 + (size_t)blkn * 128 * 1024;
  }

  f32x4 acc[4][4];
#pragma unroll
  for (int i = 0; i < 4; ++i)
#pragma unroll
    for (int j = 0; j < 4; ++j) acc[i][j] = f32x4{0.f, 0.f, 0.f, 0.f};

  for (int kc = 0; kc < kchunks; ++kc) {
    const int kbase = kc << 6;
    f16x8 rah[4], ral[4], rbh[4], rbl[4];
#pragma unroll
    for (int it = 0; it < 4; ++it) {
      const int t = tid + (it << 8);
      const int row = t >> 3, e8 = (t & 7) << 3;
      const int kcol = kbase + e8;
      if constexpr (MODE == 0) {
        const int gr = n0 + blkm * 128 + row;
        const float* ap = A32 + (size_t)gr * 512 + kcol;
        const float* sp = A32 + (size_t)(gr >> 10) * 524288 + 523776 + kcol;
        float4 a0 = *(const float4*)ap, a1 = *(const float4*)(ap + 4);
        float4 s0 = *(const float4*)sp, s1 = *(const float4*)(sp + 4);
        float v[8] = {a0.x - s0.x, a0.y - s0.y, a0.z - s0.z, a0.w - s0.w,
                      a1.x - s1.x, a1.y - s1.y, a1.z - s1.z, a1.w - s1.w};
#pragma unroll
        for (int j = 0; j < 8; ++j) {
          float w = v[j] * 16.0f;
          f16 hv = (f16)w;
          rah[it][j] = hv;
          ral[it][j] = (f16)(w - (float)hv);
        }
        rbh[it] = *(const f16x8*)(B16 + (size_t)row * 512 + kcol);
        rbl[it] = *(const f16x8*)(B16l + (size_t)row * 512 + kcol);
      } else if constexpr (MODE == 3) {
        const float* ap = A32 + (size_t)row * 512 + kcol;
        float4 a0 = *(const float4*)ap, a1 = *(const float4*)(ap + 4);
        float av[8] = {a0.x, a0.y, a0.z, a0.w, a1.x, a1.y, a1.z, a1.w};
        f16x8 hv;
#pragma unroll
        for (int j = 0; j < 8; ++j) hv[j] = (f16)av[j];
        rah[it] = hv;
        rbh[it] = *(const f16x8*)(B16 + (size_t)row * 512 + kcol);
      } else {
        rah[it] = *(const f16x8*)(A16 + (size_t)row * LDA + kcol);
        rbh[it] = *(const f16x8*)(B16 + (size_t)row * LDB + kcol);
      }
    }
    __syncthreads();
#pragma unroll
    for (int it = 0; it < 4; ++it) {
      const int t = tid + (it << 8);
      const int row = t >> 3;
      const int off = row * 128 + (((t & 7) << 4) ^ ((row & 7) << 4));
      *(f16x8*)(sA + off) = rah[it];
      *(f16x8*)(sB + off) = rbh[it];
      if constexpr (K1) { *(f16x8*)(sAl + off) = ral[it]; *(f16x8*)(sBl + off) = rbl[it]; }
    }
    __syncthreads();
#pragma unroll
    for (int ks = 0; ks < 2; ++ks) {
      const int kb = (ks << 6) + ((lane >> 4) << 4);
      f16x8 ah[4], al[4];
#pragma unroll
      for (int mt = 0; mt < 4; ++mt) {
        const int rr = wm * 64 + mt * 16 + (lane & 15);
        const int o = rr * 128 + (kb ^ ((rr & 7) << 4));
        ah[mt] = *(const f16x8*)(sA + o);
        if constexpr (K1) al[mt] = *(const f16x8*)(sAl + o);
      }
#pragma unroll
      for (int nt = 0; nt < 4; ++nt) {
        const int rn = wn * 64 + nt * 16 + (lane & 15);
        const int o = rn * 128 + (kb ^ ((rn & 7) << 4));
        f16x8 bh = *(const f16x8*)(sB + o);
        f16x8 bl;
        if constexpr (K1) bl = *(const f16x8*)(sBl + o);
#pragma unroll
        for (int mt = 0; mt < 4; ++mt) {
          if constexpr (K1) {
            acc[mt][nt] = MFMA16(al[mt], bh, acc[mt][nt]);
            acc[mt][nt] = MFMA16(ah[mt], bl, acc[mt][nt]);
          }
          acc[mt][nt] = MFMA16(ah[mt], bh, acc[mt][nt]);
        }
      }
    }
  }

  // ---- epilogues ---- C/D: col = lane&15, row = (lane>>4)*4 + reg  [m89/m91]
  if constexpr (MODE == 0) {
    float* f = (float*)out0;
#pragma unroll
    for (int nt = 0; nt < 4; ++nt) {
      const int gc = blkn * 128 + wn * 64 + nt * 16 + (lane & 15);
      const float bv = bias[gc];
#pragma unroll
      for (int mt = 0; mt < 4; ++mt)
#pragma unroll
        for (int r = 0; r < 4; ++r) {
          const size_t row_l = (size_t)blkm * 128 + wm * 64 + mt * 16 + ((lane >> 4) << 2) + r;
          f[row_l * 512 + gc] = acc[mt][nt][r] * 6.103515625e-05f + bv;  // /16384 exact
        }
    }
  } else if constexpr (MODE == 1) {
    f16* o = (f16*)out0 + (size_t)z * 524288;
#pragma unroll
    for (int nt = 0; nt < 4; ++nt) {
      const int gc = blkn * 128 + wn * 64 + nt * 16 + (lane & 15);
#pragma unroll
      for (int mt = 0; mt < 4; ++mt)
#pragma unroll
        for (int r = 0; r < 4; ++r) {
          const size_t grow = (size_t)blkm * 128 + wm * 64 + mt * 16 + ((lane >> 4) << 2) + r;
          o[grow * 512 + gc] = (f16)acc[mt][nt][r];
        }
    }
  } else if constexpr (MODE == 2) {
    float ssum = 0.f;
#pragma unroll
    for (int mt = 0; mt < 4; ++mt)
#pragma unroll
      for (int nt = 0; nt < 4; ++nt)
#pragma unroll
        for (int r = 0; r < 4; ++r) ssum += acc[mt][nt][r] * acc[mt][nt][r];
#pragma unroll
    for (int o = 1; o < 64; o <<= 1) ssum += __shfl_xor(ssum, o);
    __syncthreads();
    float* wp = (float*)lds;
    if (lane == 0) wp[wid] = ssum;
    __syncthreads();
    if (tid == 0) {
      float p = wp[0] + wp[1] + wp[2] + wp[3];
      atomicAdd(slots + (blockIdx.x & 63), (u64)llrintf(p * 16777216.f));
    }
  } else if constexpr (MODE == 3) {
    u64* candL = (u64*)(lds + 32768);
    int* cntL = (int*)(lds + 40960);
    u64* candG = (u64*)out0;
    float escol[4];
    int cg[4];
#pragma unroll
    for (int nt = 0; nt < 4; ++nt) {
      cg[nt] = blkn * 128 + wn * 64 + nt * 16 + (lane & 15);
      escol[nt] = aux[cg[nt]];
    }
#pragma unroll
    for (int mt = 0; mt < 4; ++mt)
#pragma unroll
      for (int r = 0; r < 4; ++r) {
        const int row_l = wm * 64 + mt * 16 + ((lane >> 4) << 2) + r;
        float vals[4];
        u64 pk[4];
        u64 mn = ~0ull;
#pragma unroll
        for (int nt = 0; nt < 4; ++nt) {
          const float v = escol[nt] - 2.0f * acc[mt][nt][r];
          vals[nt] = v;
          const u64 p = ((u64)ford(v) << 32) | (u32)cg[nt];
          pk[nt] = p;
          if (p < mn) mn = p;
        }
#pragma unroll
        for (int o = 1; o < 16; o <<= 1) {  // 16-lane group = one row's 64 cols (this wave-half)
          const u64 t = __shfl_xor(mn, o);
          if (t < mn) mn = t;
        }
        const float lim = iford((u32)(mn >> 32)) + MARGIN;
#pragma unroll
        for (int nt = 0; nt < 4; ++nt)
          if (vals[nt] <= lim) {
            const int p = atomicAdd(&cntL[row_l], 1);
            if (p < 8) candL[(row_l << 3) + p] = pk[nt];
          }
      }
    __syncthreads();
#pragma unroll
    for (int j = 0; j < 4; ++j) {
      const int idx = tid * 4 + j;
      const int row_l = idx >> 3, slot = idx & 7;
      candG[(((size_t)blkm * 128 + row_l) * 8 + blkn) * 8 + slot] = candL[idx];
    }
  } else {  // MODE 4
    float* oy = (float*)out0 + (size_t)z * 368640;
    const float* xseq = aux + (size_t)z * 524288 + 523776;
    float sl[4];
    int gd[4];
#pragma unroll
    for (int nt = 0; nt < 4; ++nt) {
      gd[nt] = blkn * 128 + wn * 64 + nt * 16 + (lane & 15);
      sl[nt] = xseq[gd[nt]];
    }
#pragma unroll
    for (int mt = 0; mt < 4; ++mt)
#pragma unroll
      for (int r = 0; r < 4; ++r) {
        const int p = blkm * 128 + wm * 64 + mt * 16 + ((lane >> 4) << 2) + r;
        if (p < 720) {
          const float bp = bias[p];
#pragma unroll
          for (int nt = 0; nt < 4; ++nt) oy[(size_t)p * 512 + gd[nt]] = acc[mt][nt][r] + bp + sl[nt];
        }
      }
  }
}

// ---------------------------------------------------------------------------
// Rescore: per row, exact fp64 distances (fp32 f vs fp32 embed) over margin set.
// ---------------------------------------------------------------------------
__global__ __launch_bounds__(256, 4) void rescore_k(
    const u64* __restrict__ candG, const float* __restrict__ f,
    const float* __restrict__ embedH, int n0, int h,
    int* __restrict__ indw, float* __restrict__ indout, u64* __restrict__ cslots) {
  const int tid = threadIdx.x, lane = tid & 63, wid = tid >> 6;
  const int r = blockIdx.x * 4 + wid;  // [0,16384)
  u64 cu = candG[(size_t)r * 64 + lane];
  u64 mn = cu;
#pragma unroll
  for (int o = 1; o < 64; o <<= 1) { const u64 t = __shfl_xor(mn, o); if (t < mn) mn = t; }
  const float lim = iford((u32)(mn >> 32)) + MARGIN;
  const bool pass = iford((u32)(cu >> 32)) <= lim;  // empty slots -> NaN -> false
  u64 mask = __ballot(pass);
  const float* fp = f + (size_t)r * 512 + lane * 8;
  const float4 f0 = *(const float4*)fp, f1 = *(const float4*)(fp + 4);
  const float fv[8] = {f0.x, f0.y, f0.z, f0.w, f1.x, f1.y, f1.z, f1.w};
  double bestd = 1e300;
  int bestc = 0x7FFFFFFF;
  while (mask) {
    const int src = __ffsll((unsigned long long)mask) - 1;
    mask &= mask - 1;
    const int c = (int)(u32)__shfl(cu, src);
    const float* e = embedH + (size_t)c * 512 + lane * 8;
    const float4 e0 = *(const float4*)e, e1 = *(const float4*)(e + 4);
    const float ev[8] = {e0.x, e0.y, e0.z, e0.w, e1.x, e1.y, e1.z, e1.w};
    double sd = 0.0;
#pragma unroll
    for (int j = 0; j < 8; ++j) { const double d = (double)fv[j] - (double)ev[j]; sd += d * d; }
#pragma unroll
    for (int o = 1; o < 64; o <<= 1) sd += __shfl_xor(sd, o);
    if (sd < bestd || (sd == bestd && c < bestc)) { bestd = sd; bestc = c; }
  }
  if (lane == 0) {
    const int n = n0 + r;
    indw[(size_t)n * 4 + h] = bestc;
    indout[(size_t)n * 4 + h] = (float)bestc;
    atomicAdd(cslots + (r & 255), (u64)llrint(bestd * 65536.0));
  }
}

// quantized^T gather: qT[b][d][s] = f16( b_out[d] + sum_h Ep[h][ind[b,s,h]][d] )
__global__ __launch_bounds__(256) void quantize_qT(
    const int* __restrict__ indw, const f16* __restrict__ Ep,
    const float* __restrict__ b_out, f16* __restrict__ qT) {
  const int tid = threadIdx.x;
  const int b = blockIdx.x >> 4, s0 = (blockIdx.x & 15) << 6;
  __shared__ int inds[64][4];
  inds[tid >> 2][tid & 3] = indw[(size_t)(b * 1024 + s0 + (tid >> 2)) * 4 + (tid & 3)];
  __syncthreads();
  const int d0 = tid * 2;
  const float ba0 = b_out[d0], ba1 = b_out[d0 + 1];
  u32 r0[32], r1[32];
  f16 t0 = (f16)0.f, t1 = (f16)0.f;
#pragma unroll
  for (int ss = 0; ss < 64; ++ss) {
    float a0 = ba0, a1 = ba1;
#pragma unroll
    for (int h = 0; h < 4; ++h) {
      const int c = inds[ss][h];
      const f16x2 p = *(const f16x2*)(Ep + (((size_t)h * 1024 + c) * 512 + d0));
      a0 += (float)p[0];
      a1 += (float)p[1];
    }
    const f16 q0 = (f16)a0, q1 = (f16)a1;
    if (ss & 1) {
      f16x2 w0; w0[0] = t0; w0[1] = q0; __builtin_memcpy(&r0[ss >> 1], &w0, 4);
      f16x2 w1; w1[0] = t1; w1[1] = q1; __builtin_memcpy(&r1[ss >> 1], &w1, 4);
    } else { t0 = q0; t1 = q1; }
  }
  const size_t o0 = ((size_t)b * 512 + d0) * 1024 + s0;
#pragma unroll
  for (int i = 0; i < 8; ++i) {
    uint4 v; v.x = r0[4 * i]; v.y = r0[4 * i + 1]; v.z = r0[4 * i + 2]; v.w = r0[4 * i + 3];
    *(uint4*)(qT + o0 + (size_t)i * 8) = v;
  }
  const size_t o1 = o0 + 1024;
#pragma unroll
  for (int i = 0; i < 8; ++i) {
    uint4 v; v.x = r1[4 * i]; v.y = r1[4 * i + 1]; v.z = r1[4 * i + 2]; v.w = r1[4 * i + 3];
    *(uint4*)(qT + o1 + (size_t)i * 8) = v;
  }
}

// ---- prep kernels ----
__global__ __launch_bounds__(256) void prep_win(const float* __restrict__ src,
                                                f16* __restrict__ hi, f16* __restrict__ lo) {
  const size_t e = ((size_t)blockIdx.x * 256 + threadIdx.x) * 4;
  const float4 v = *(const float4*)(src + e);
  const float w[4] = {v.x * 1024.f, v.y * 1024.f, v.z * 1024.f, v.w * 1024.f};
  f16x4 hv, lv;
#pragma unroll
  for (int j = 0; j < 4; ++j) { const f16 h = (f16)w[j]; hv[j] = h; lv[j] = (f16)(w[j] - (float)h); }
  *(f16x4*)(hi + e) = hv;
  *(f16x4*)(lo + e) = lv;
}

__global__ __launch_bounds__(256) void prep_cast16(const float* __restrict__ src,
                                                   f16* __restrict__ dst) {
  const size_t e = ((size_t)blockIdx.x * 256 + threadIdx.x) * 4;
  const float4 v = *(const float4*)(src + e);
  f16x4 o; o[0] = (f16)v.x; o[1] = (f16)v.y; o[2] = (f16)v.z; o[3] = (f16)v.w;
  *(f16x4*)(dst + e) = o;
}

__global__ __launch_bounds__(256) void prep_wlin(const float* __restrict__ src,
                                                 f16* __restrict__ dst) {
  const size_t e = ((size_t)blockIdx.x * 256 + threadIdx.x) * 4;  // 768x1024 padded
  const int row = (int)(e >> 10), col = (int)(e & 1023);
  float4 v = {0.f, 0.f, 0.f, 0.f};
  if (row < 720) v = *(const float4*)(src + (size_t)row * 1024 + col);
  f16x4 o; o[0] = (f16)v.x; o[1] = (f16)v.y; o[2] = (f16)v.z; o[3] = (f16)v.w;
  *(f16x4*)(dst + e) = o;
}

__global__ __launch_bounds__(256) void prep_embed_k(const float* __restrict__ em,
                                                    f16* __restrict__ ef,
                                                    float* __restrict__ esq,
                                                    float* __restrict__ invn) {
  const int tid = threadIdx.x, lane = tid & 63, wid = tid >> 6;
  const int row = blockIdx.x * 4 + wid;  // 0..4095 = h*1024+c
  const float* er = em + (size_t)row * 512 + lane * 8;
  const float4 a = *(const float4*)er, b = *(const float4*)(er + 4);
  f16x8 v;
  v[0] = (f16)a.x; v[1] = (f16)a.y; v[2] = (f16)a.z; v[3] = (f16)a.w;
  v[4] = (f16)b.x; v[5] = (f16)b.y; v[6] = (f16)b.z; v[7] = (f16)b.w;
  *(f16x8*)(ef + (size_t)row * 512 + lane * 8) = v;
  float s = a.x * a.x + a.y * a.y + a.z * a.z + a.w * a.w +
            b.x * b.x + b.y * b.y + b.z * b.z + b.w * b.w;
#pragma unroll
  for (int o = 1; o < 64; o <<= 1) s += __shfl_xor(s, o);
  if (lane == 0) { esq[row] = s; invn[row] = 1.0f / sqrtf(s); }
}

__global__ __launch_bounds__(256) void prep_normT(const float* __restrict__ em,
                                                  const float* __restrict__ invn,
                                                  f16* __restrict__ nT) {
  __shared__ float t[64 * 65];
  const int tid = threadIdx.x;
  const int bx = blockIdx.x;  // 512
  const int h = bx >> 7, rem = bx & 127, cb = rem >> 3, db = rem & 7;
  const int c0 = cb * 64, d0 = db * 64;
  const int j = tid & 63, i0 = tid >> 6;
#pragma unroll
  for (int p = 0; p < 16; ++p) {
    const int i = p * 4 + i0;
    t[i * 65 + j] = em[(size_t)h * 524288 + (size_t)(c0 + i) * 512 + d0 + j] * invn[h * 1024 + c0 + i];
  }
  __syncthreads();
#pragma unroll
  for (int p = 0; p < 16; ++p) {
    const int i = p * 4 + i0;
    nT[(size_t)h * 524288 + (size_t)(d0 + i) * 1024 + c0 + j] = (f16)t[j * 65 + i];
  }
}

__global__ void finalize_k(const u64* __restrict__ cs, const u64* __restrict__ gs,
                           float* __restrict__ out) {
  const int lane = threadIdx.x;  // 64
  u64 c = cs[lane] + cs[lane + 64] + cs[lane + 128] + cs[lane + 192];
  u64 g = gs[lane];
#pragma unroll
  for (int o = 1; o < 64; o <<= 1) {
    c += __shfl_xor(c, o);
    g += __shfl_xor(g, o);
  }
  if (lane == 0) {
    const double commit = (double)c / 65536.0 / 67108864.0;      // / (H*B*S*D)
    const double ortho = (double)g / 16777216.0 / 4194304.0 - (1.0 / 1024.0);
    out[11927552] = (float)(commit + 0.8 * ortho);
  }
}

__global__ void ws_fail_k(float* out) {
  if (threadIdx.x == 0) out[11927552] = -777777.0f;  // sentinel: ws too small
}

// ---------------------------------------------------------------------------
extern "C" void kernel_launch(void* const* d_in, const int* in_sizes, int n_in,
                              void* d_out, int out_size, void* d_ws, size_t ws_size,
                              hipStream_t stream) {
  (void)in_sizes; (void)n_in; (void)out_size;
  const float* x = (const float*)d_in[0];
  const float* w_in = (const float*)d_in[1];
  const float* b_in = (const float*)d_in[2];
  const float* embed = (const float*)d_in[3];
  const float* w_out = (const float*)d_in[4];
  const float* b_out = (const float*)d_in[5];
  const float* w_lin = (const float*)d_in[6];
  const float* b_lin = (const float*)d_in[7];
  float* out = (float*)d_out;
  char* ws = (char*)d_ws;

  constexpr size_t OFF_F = 0;              // 32MB fp32 f (per pass), aliased by qT later
  constexpr size_t OFF_CAND = 33554432;    // 8MB
  constexpr size_t OFF_WINH = 41943040;    // 2MB f16
  constexpr size_t OFF_WINL = 44040192;    // 2MB
  constexpr size_t OFF_EF = 46137344;      // 4MB
  constexpr size_t OFF_NT = 50331648;      // 4MB
  constexpr size_t OFF_EP = 54525952;      // 4MB
  constexpr size_t OFF_WOUT = 58720256;    // 2MB
  constexpr size_t OFF_WLIN = 60817408;    // 1.5MB
  constexpr size_t OFF_ESQ = 62390272;     // 16KB
  constexpr size_t OFF_INVN = 62406656;    // 16KB
  constexpr size_t OFF_INDW = 62423040;    // 512KB
  constexpr size_t OFF_CSL = 62947328;     // 2KB
  constexpr size_t OFF_GSL = 62949376;     // 512B
  constexpr size_t REQUIRED = 62949888;

  if (ws_size < REQUIRED) {
    ws_fail_k<<<1, 64, 0, stream>>>(out);
    return;
  }

  float* f = (float*)(ws + OFF_F);
  u64* cand = (u64*)(ws + OFF_CAND);
  f16* winhi = (f16*)(ws + OFF_WINH);
  f16* winlo = (f16*)(ws + OFF_WINL);
  f16* ef = (f16*)(ws + OFF_EF);
  f16* nT = (f16*)(ws + OFF_NT);
  f16* Ep = (f16*)(ws + OFF_EP);
  f16* woutf = (f16*)(ws + OFF_WOUT);
  f16* wlinp = (f16*)(ws + OFF_WLIN);
  float* esq = (float*)(ws + OFF_ESQ);
  float* invn = (float*)(ws + OFF_INVN);
  int* indw = (int*)(ws + OFF_INDW);
  u64* cslots = (u64*)(ws + OFF_CSL);
  u64* gslots = (u64*)(ws + OFF_GSL);
  f16* qT = (f16*)(ws + OFF_F);  // aliases f after last rescore

  hipMemsetAsync(ws + OFF_CSL, 0, 2560, stream);

  prep_win<<<1024, 256, 0, stream>>>(w_in, winhi, winlo);
  prep_embed_k<<<1024, 256, 0, stream>>>(embed, ef, esq, invn);
  prep_normT<<<512, 256, 0, stream>>>(embed, invn, nT);
  prep_cast16<<<1024, 256, 0, stream>>>(w_out, woutf);
  prep_wlin<<<768, 256, 0, stream>>>(w_lin, wlinp);

  // E'[h] = embed_h @ w_out_h^T   (f16)
  gemm_nt<1><<<128, 256, 0, stream>>>(nullptr, ef, woutf, nullptr, 0, 8, Ep,
                                      nullptr, nullptr, nullptr);
  // ortho: ||N_h^T N_h||_F^2
  gemm_nt<2><<<64, 256, 0, stream>>>(nullptr, nT, nT, nullptr, 0, 16, nullptr,
                                     nullptr, nullptr, gslots);

  for (int h = 0; h < 4; ++h) {
    const f16* winhiH = winhi + (size_t)h * 262144;
    const f16* winloH = winlo + (size_t)h * 262144;
    const f16* efH = ef + (size_t)h * 524288;
    const float* esqH = esq + (size_t)h * 1024;
    const float* embedH = embed + (size_t)h * 524288;
    const float* b_inH = b_in + (size_t)h * 512;
    for (int half = 0; half < 2; ++half) {
      const int n0 = half * 16384;
      // f = ((x - seq_last) @ w_in_h^T + b_in_h), split-f16 3-pass, fp32 out
      gemm_nt<0><<<512, 256, 0, stream>>>(x, nullptr, winhiH, winloH, n0, 8, f,
                                          b_inH, nullptr, nullptr);
      // screen scores + margin candidates
      gemm_nt<3><<<1024, 256, 0, stream>>>(f, nullptr, efH, nullptr, 0, 8, cand,
                                           nullptr, esqH, nullptr);
      // exact rescore -> indices + commit d^2
      rescore_k<<<4096, 256, 0, stream>>>(cand, f, embedH, n0, h, indw,
                                          out + 11796480, cslots);
    }
  }

  quantize_qT<<<512, 256, 0, stream>>>(indw, Ep, b_out, qT);
  // y = w_lin @ quantized + b_lin + seq_last
  gemm_nt<4><<<768, 256, 0, stream>>>(nullptr, wlinp, qT, nullptr, 0, 16, out,
                                      b_lin, x, nullptr);
  finalize_k<<<1, 64, 0, stream>>>(cslots, gslots, out);
}